// Round 6
// baseline (205.494 us; speedup 1.0000x reference)
//
#include <hip/hip_runtime.h>
#include <cmath>

// ---------------------------------------------------------------------------
// NeuralField: hashgrid encode (8 levels x 8 feats, smoothstep) + MLP
// 64 -> 256 -> 256 -> 256 -> 1 (ReLU x3, linear out), N = 262144 points.
// R6: R5's transposed-MFMA structure + R3's 40 KB in-place LDS scheme
// (8 KB enc + ONE 32 KB act buffer, extra mid-layer sync), while KEEPING
// __launch_bounds__(256,2) (256-reg budget). R3/R4 proved tighter reg caps
// spill the accumulators (300-700 MB scratch HBM); R5 proved (256,2) is
// spill-free at ~152 total regs. 152 regs -> 3 waves/SIMD, 40 KB -> 4
// blocks/CU by LDS => occupancy 2 -> 3 blocks/CU (12 waves/CU).
// ---------------------------------------------------------------------------

#define N_LEVELS 8
#define TABLE_PAD 8192
#define TILE_M 64
#define ACT_STRIDE 256       // shorts per activation row
#define ENC_STRIDE 64        // shorts per encode row

typedef __attribute__((ext_vector_type(8))) short short8;
typedef __attribute__((ext_vector_type(4))) short short4v;
typedef __attribute__((ext_vector_type(4))) float float4v;

struct LevelParams {
  float scale[N_LEVELS];
  int   res[N_LEVELS];
  int   size[N_LEVELS];
};

__device__ __forceinline__ unsigned short f2bf(float f) {
  unsigned int u = __float_as_uint(f);
  u += 0x7fffu + ((u >> 16) & 1u);      // round to nearest even
  return (unsigned short)(u >> 16);
}
__device__ __forceinline__ float bf2f(unsigned short h) {
  return __uint_as_float(((unsigned int)h) << 16);
}

// Pack W (K x 256 row-major f32) -> bf16 [kb][n][ki]: one lane's 16 B A-frag
// (output-feature n, k-chunk) is contiguous; a wave's 16 n x 32 k tile is a
// coalesced 1 KB chunk. Wp layout: [W0p: 2*256*32][W1p+W2p: 8*256*32 each]
__global__ void pack_weights_kernel(const float* __restrict__ W0,
                                    const float* __restrict__ W1,
                                    const float* __restrict__ W2,
                                    unsigned short* __restrict__ Wp) {
  int tid = blockIdx.x * blockDim.x + threadIdx.x;
  const float* src;
  int base, e;
  if (tid < 16384)        { src = W0; base = 0;     e = tid;         }
  else if (tid < 81920)   { src = W1; base = 16384; e = tid - 16384; }
  else if (tid < 147456)  { src = W2; base = 81920; e = tid - 81920; }
  else return;
  int ki = e & 31;
  int n  = (e >> 5) & 255;
  int kb = e >> 13;
  Wp[base + e] = f2bf(src[(kb * 32 + ki) * 256 + n]);
}

__global__ __launch_bounds__(256, 2) void neural_field_kernel(
    const float* __restrict__ x,
    const float* __restrict__ table,
    const unsigned short* __restrict__ Wp,
    const float* __restrict__ W3,
    float* __restrict__ out,
    LevelParams P) {
  // XOR-swizzled layouts (16 B granular), data stored [point m][feature k]:
  //   enc (stride 64):  (m, k) -> m*64  + ((chunk ^ (m&7)) *8 + k&7)
  //   act (stride 256): (m, k) -> m*256 + ((chunk ^ (m&15))*8 + k&7)
  __shared__ unsigned short bufE[TILE_M * ENC_STRIDE];   // 8 KB
  __shared__ unsigned short bufA[TILE_M * ACT_STRIDE];   // 32 KB

  const int t  = threadIdx.x;
  const int g0 = blockIdx.x * TILE_M;

  // ---------------- Phase 1: hashgrid encode -> bufE (K=64) ----------------
  {
    int p  = t & 63;       // point within tile
    int lg = t >> 6;       // 0..3 -> handles levels 2lg, 2lg+1
    float2 xy = ((const float2*)x)[g0 + p];
    for (int li = 0; li < 2; ++li) {
      int l = lg * 2 + li;
      float scale = P.scale[l];
      int res = P.res[l], size = P.size[l];
      float posx = xy.x * scale + 0.5f;
      float posy = xy.y * scale + 0.5f;
      float pgx = floorf(posx), pgy = floorf(posy);
      float fx = posx - pgx, fy = posy - pgy;
      float wx = fx * fx * (3.0f - 2.0f * fx);
      float wy = fy * fy * (3.0f - 2.0f * fy);
      int px = (int)pgx, py = (int)pgy;
      float acc[8] = {0, 0, 0, 0, 0, 0, 0, 0};
      for (int dy = 0; dy < 2; ++dy) {
        float wyv = dy ? wy : 1.0f - wy;
        for (int dx = 0; dx < 2; ++dx) {
          float wgt = (dx ? wx : 1.0f - wx) * wyv;
          int idx = (px + dx) + (py + dy) * res;
          if (idx >= size) idx -= size;   // idx < 2*size always
          const float4* tp =
              (const float4*)(table + ((size_t)l * TABLE_PAD + idx) * 8);
          float4 t0 = tp[0], t1 = tp[1];
          acc[0] += wgt * t0.x; acc[1] += wgt * t0.y;
          acc[2] += wgt * t0.z; acc[3] += wgt * t0.w;
          acc[4] += wgt * t1.x; acc[5] += wgt * t1.y;
          acc[6] += wgt * t1.z; acc[7] += wgt * t1.w;
        }
      }
      union { unsigned short s[8]; short8 v; } u;
      for (int j = 0; j < 8; ++j) u.s[j] = f2bf(acc[j]);
      int pos = (l ^ (p & 7)) * 8;        // chunk l, swizzled (8 chunks)
      *(short8*)&bufE[p * ENC_STRIDE + pos] = u.v;
    }
  }

  const int lane  = t & 63;
  const int w     = t >> 6;       // 0..3
  const int l15   = lane & 15;
  const int quad  = lane >> 4;
  const int wbase = w * 64;       // this wave's 64 OUTPUT FEATURES

  // ------- MFMA layer (transposed): D = W^T[64 x K] @ X^T[K x 64] ----------
  // A-frag = weights: lane row n = wbase+ft*16+l15, k = quad*8..+7.
  // B-frag = acts:    lane col m = pt*16+l15,       k = quad*8..+7.
  // D runs along n (feature dim) -> epilogue packs 4 bf16 -> one b64 write
  // per tile, already in the [m][k-contiguous] layout the next layer reads.
  // inplace: extra barrier between last K-loop read and epilogue overwrite.
  auto run_layer = [&](const unsigned short* inb, int in_stride, int smask,
                       unsigned short* outb, const unsigned short* Wpl,
                       int KB, bool inplace) {
    float4v acc[4][4];   // [ft][pt]
    for (int ft = 0; ft < 4; ++ft)
      for (int pt = 0; pt < 4; ++pt)
        acc[ft][pt] = (float4v){0.f, 0.f, 0.f, 0.f};

    for (int kb = 0; kb < KB; ++kb) {
      short8 wf[4], af[4];
      for (int ft = 0; ft < 4; ++ft) {
        int n = wbase + ft * 16 + l15;
        wf[ft] = *(const short8*)&Wpl[(kb * 256 + n) * 32 + quad * 8];
      }
      int kchunk = kb * 4 + quad;
      for (int pt = 0; pt < 4; ++pt) {
        int m = pt * 16 + l15;
        int pos = (kchunk ^ (m & smask)) * 8;
        af[pt] = *(const short8*)&inb[m * in_stride + pos];
      }
      for (int ft = 0; ft < 4; ++ft)
        for (int pt = 0; pt < 4; ++pt)
          acc[ft][pt] = __builtin_amdgcn_mfma_f32_16x16x32_bf16(
              wf[ft], af[pt], acc[ft][pt], 0, 0, 0);
    }

    if (inplace) __syncthreads();   // all reads done before overwrite

    // Epilogue: ReLU + bf16, one ds_write_b64 per tile.
    for (int ft = 0; ft < 4; ++ft) {
      int n0 = wbase + ft * 16 + quad * 4;
      int chunk = n0 >> 3, within = n0 & 7;       // within in {0,4}
      for (int pt = 0; pt < 4; ++pt) {
        int m = pt * 16 + l15;
        union { unsigned short s[4]; short4v v; } u;
        for (int r = 0; r < 4; ++r) {
          float v = acc[ft][pt][r];
          u.s[r] = f2bf(v > 0.f ? v : 0.f);
        }
        int pos = (chunk ^ (m & 15)) * 8 + within;
        *(short4v*)&outb[m * ACT_STRIDE + pos] = u.v;
      }
    }
  };

  __syncthreads();
  run_layer(bufE, ENC_STRIDE, 7,  bufA, Wp,         2, false);  // layer 0
  __syncthreads();
  run_layer(bufA, ACT_STRIDE, 15, bufA, Wp + 16384, 8, true);   // layer 1
  __syncthreads();
  run_layer(bufA, ACT_STRIDE, 15, bufA, Wp + 81920, 8, true);   // layer 2
  __syncthreads();

  // ---------------- Final layer: out[p] = h2[p] . W3 -----------------------
  {
    int p = t >> 2;          // point within tile (0..63)
    int q = t & 3;           // quarter of K=256
    float s = 0.f;
    for (int c8 = 0; c8 < 8; ++c8) {
      int chunk = q * 8 + c8;
      int pos = (chunk ^ (p & 15)) * 8;
      short8 h = *(const short8*)&bufA[p * ACT_STRIDE + pos];
      float4 w0v = *(const float4*)(W3 + chunk * 8);
      float4 w1v = *(const float4*)(W3 + chunk * 8 + 4);
      s += bf2f((unsigned short)h[0]) * w0v.x;
      s += bf2f((unsigned short)h[1]) * w0v.y;
      s += bf2f((unsigned short)h[2]) * w0v.z;
      s += bf2f((unsigned short)h[3]) * w0v.w;
      s += bf2f((unsigned short)h[4]) * w1v.x;
      s += bf2f((unsigned short)h[5]) * w1v.y;
      s += bf2f((unsigned short)h[6]) * w1v.z;
      s += bf2f((unsigned short)h[7]) * w1v.w;
    }
    s += __shfl_xor(s, 1);
    s += __shfl_xor(s, 2);
    if (q == 0) out[g0 + p] = s;
  }
}

extern "C" void kernel_launch(void* const* d_in, const int* in_sizes, int n_in,
                              void* d_out, int out_size, void* d_ws,
                              size_t ws_size, hipStream_t stream) {
  const float* x     = (const float*)d_in[0];
  const float* table = (const float*)d_in[1];
  const float* W0    = (const float*)d_in[2];
  const float* W1    = (const float*)d_in[3];
  const float* W2    = (const float*)d_in[4];
  const float* W3    = (const float*)d_in[5];
  float* out = (float*)d_out;
  int N = in_sizes[0] / 2;

  unsigned short* Wp = (unsigned short*)d_ws;   // 147456 bf16 = 288 KB

  // Level params, double precision to match the Python reference exactly.
  LevelParams P;
  const double c = 1.2599210739135742;
  double m = 1.0;
  for (int l = 0; l < N_LEVELS; ++l) {
    double scale_d = 16.0 * m - 1.0;
    int res = (int)std::ceil(scale_d) + 1;
    long long sz = ((long long)res * res + 7) / 8 * 8;
    if (sz > (1LL << 19)) sz = 1LL << 19;
    P.scale[l] = (float)scale_d;
    P.res[l]   = res;
    P.size[l]  = (int)sz;
    m *= c;
  }

  hipLaunchKernelGGL(pack_weights_kernel, dim3(576), dim3(256), 0, stream,
                     W0, W1, W2, Wp);
  hipLaunchKernelGGL(neural_field_kernel, dim3(N / TILE_M), dim3(256), 0,
                     stream, x, table, Wp, W3, out, P);
}